// Round 14
// baseline (59.464 us; speedup 1.0000x reference)
//
#include <hip/hip_runtime.h>

// SparsTriangularUpdate — round 14: 32x32x16 MFMA (halve operand fetch/row).
//
// Closed form (verified): c[t] = a[:,t*16,:]*b[:,t*16,:];
//   k[:,t*16+s,:] = sum_{m=s+2}^{16} c[:,(t+m)%4096,:]  (s=0..15; s=15 -> 0)
//
// R5->R6 win tracked TRANSACTION removal (bytes unchanged); R12's LDS-weights
// null is consistent (same traffic on the ds pipe). Wall model: per-CU operand
// fetch throughput; weights = 64KB/wave under 16x16 MFMA. R14: 32x32x16 MFMA
// -> 4x output per instruction, weight+A fetch per row halved. Raw-k GEMM +
// algebraic LN epilogue kept from R13 (proven numerics).

#define BB 2
#define NN 65536
#define DD 128
#define CC 128
#define NA 4096
#define STR 16
#define WSZ 16384   // elements per weight matrix

typedef short short4v __attribute__((ext_vector_type(4)));
typedef short short8v __attribute__((ext_vector_type(8)));
typedef __bf16 bf16x8 __attribute__((ext_vector_type(8)));
typedef float f32x4 __attribute__((ext_vector_type(4)));
typedef float f32x2 __attribute__((ext_vector_type(2)));
typedef float f32x16 __attribute__((ext_vector_type(16)));

__device__ __forceinline__ float sigf(float v) { return 1.0f / (1.0f + __expf(-v)); }
__device__ __forceinline__ short nbf(float f) {           // native RTNE f32->bf16
    union { __bf16 h; short s; } u; u.h = (__bf16)f; return u.s;
}
__device__ __forceinline__ float bf2f(short b) {
    union { unsigned u; float f; } v; v.u = ((unsigned)(unsigned short)b) << 16;
    return v.f;
}
__device__ __forceinline__ bf16x8 s2b(short8v s) {
    union { short8v s; bf16x8 b; } u; u.s = s; return u.b;
}

// wcvt: matrices 0-3 in 16x16 fragment order (kern_ab);
//       matrices 4-5 in 32x32 fragment order (kern_out):
//   pos32(ch,d) = ((ch>>5)*8 + (d>>4))*512 + (((d>>3)&1)*32 + (ch&31))*8 + (d&7)
//   lane l reads tile (nt,kb) at wptr + (nt*8+kb)*512 + l*8 (coalesced 1KB).
__global__ __launch_bounds__(256)
void kern_wcvt(const float* __restrict__ Wla, const float* __restrict__ Wga,
               const float* __restrict__ Wlb, const float* __restrict__ Wgb,
               const float* __restrict__ Wgo, const float* __restrict__ Wlo,
               const float* __restrict__ lnw, const float* __restrict__ lnb,
               const float* __restrict__ lnow, const float* __restrict__ lnob,
               const float* __restrict__ bla, const float* __restrict__ bga,
               const float* __restrict__ blb, const float* __restrict__ bgb,
               const float* __restrict__ bgo, const float* __restrict__ blo,
               short* __restrict__ wbf, float* __restrict__ vtab)
{
    const int b = blockIdx.x;
    if (b < 64) {
        const int i  = b * 256 + threadIdx.x;
        const int ch = i >> 7, d = i & 127;
        const int pos16 = ((ch >> 4) * 4 + (d >> 5)) * 512
                        + ((((d >> 3) & 3) * 16 + (ch & 15)) * 8) + (d & 7);
        const int pos32 = ((ch >> 5) * 8 + (d >> 4)) * 512
                        + ((((d >> 3) & 1) * 32 + (ch & 31)) * 8) + (d & 7);
        const float wi = lnw[d], wo = lnow[d];
        wbf[pos16]           = nbf(Wla[i] * wi);
        wbf[WSZ + pos16]     = nbf(Wga[i] * wi);
        wbf[2 * WSZ + pos16] = nbf(Wlb[i] * wi);
        wbf[3 * WSZ + pos16] = nbf(Wgb[i] * wi);
        wbf[4 * WSZ + pos32] = nbf(Wgo[i] * wi);
        wbf[5 * WSZ + pos32] = nbf(Wlo[i] * wo);
    } else {
        // v_m[c] = sum_d W_m[c,d]*b_m[d] + bias_m[c]
        // s_m[c] = sum_d W_m[c,d]*w_m[d]
        const int t = (b - 64) * 256 + threadIdx.x;     // 0..767
        const int m = t >> 7, c = t & 127;
        const float* Wr = (m == 0) ? Wla : (m == 1) ? Wga : (m == 2) ? Wlb
                        : (m == 3) ? Wgb : (m == 4) ? Wgo : Wlo;
        const float* bb = (m == 5) ? lnob : lnb;
        const float* ww = (m == 5) ? lnow : lnw;
        const float* bi = (m == 0) ? bla : (m == 1) ? bga : (m == 2) ? blb
                        : (m == 3) ? bgb : (m == 4) ? bgo : blo;
        const float* row = Wr + (size_t)c * DD;
        float av = 0.f, as = 0.f;
        for (int d = 0; d < DD; d += 4) {
            const f32x4 w4 = *(const f32x4*)(row + d);
            const f32x4 b4 = *(const f32x4*)(bb + d);
            const f32x4 g4 = *(const f32x4*)(ww + d);
            av += w4[0]*b4[0] + w4[1]*b4[1] + w4[2]*b4[2] + w4[3]*b4[3];
            as += w4[0]*g4[0] + w4[1]*g4[1] + w4[2]*g4[2] + w4[3]*g4[3];
        }
        vtab[m * 128 + c]       = av + bi[c];
        vtab[768 + m * 128 + c] = as;
    }
}

__global__ __launch_bounds__(256)
void kern_ab(const float* __restrict__ x, const short* __restrict__ wbf,
             const float* __restrict__ vtab, float* __restrict__ cbuf)
{
    const int wv    = threadIdx.x >> 6;
    const int l     = threadIdx.x & 63;
    const int bid   = blockIdx.x * 4 + wv;    // 0..1023 (4 waves/block)
    const int batch = bid >> 9;
    const int t0    = ((bid & 511) >> 1) << 4;
    const int nt0   = (bid & 1) * 4;          // nt half: cols [nt0*16, +64)
    const int lr    = l & 15;
    const int q     = l >> 4;
    const int fl    = l * 8;

    const float* xr = x + ((size_t)batch * NN + (size_t)(t0 + lr) * STR) * DD + q * 8;
    f32x4 v[4][2];
    #pragma unroll
    for (int kk = 0; kk < 4; ++kk) {
        v[kk][0] = *(const f32x4*)(xr + kk * 32);
        v[kk][1] = *(const f32x4*)(xr + kk * 32 + 4);
    }
    float s = 0.f, ss = 0.f;
    #pragma unroll
    for (int kk = 0; kk < 4; ++kk)
        #pragma unroll
        for (int h = 0; h < 2; ++h)
            #pragma unroll
            for (int j = 0; j < 4; ++j) { const float f = v[kk][h][j]; s += f; ss += f * f; }
    s += __shfl_xor(s, 16); ss += __shfl_xor(ss, 16);
    s += __shfl_xor(s, 32); ss += __shfl_xor(ss, 32);
    const float mu = s * (1.0f / 128.0f);
    const float rs = rsqrtf(ss * (1.0f / 128.0f) - mu * mu + 1e-5f);
    const float p  = -mu * rs;

    bf16x8 af[4];
    #pragma unroll
    for (int kk = 0; kk < 4; ++kk) {
        short8v t;
        #pragma unroll
        for (int j = 0; j < 4; ++j) {
            t[j]     = nbf(v[kk][0][j] * rs + p);
            t[4 + j] = nbf(v[kk][1][j] * rs + p);
        }
        af[kk] = s2b(t);
    }

    const short* wla = wbf;
    const short* wga = wbf + WSZ;
    const short* wlb = wbf + 2 * WSZ;
    const short* wgb = wbf + 3 * WSZ;

    #pragma unroll
    for (int nt = 0; nt < 4; ++nt) {
        const int col  = (nt0 + nt) * 16 + lr;
        const int base = ((nt0 + nt) * 4) * 512 + fl;
        f32x4 ala = {0.f,0.f,0.f,0.f}, aga = {0.f,0.f,0.f,0.f};
        f32x4 alb = {0.f,0.f,0.f,0.f}, agb = {0.f,0.f,0.f,0.f};
        #pragma unroll
        for (int kk = 0; kk < 4; ++kk) {
            const int o = base + kk * 512;
            ala = __builtin_amdgcn_mfma_f32_16x16x32_bf16(af[kk], *(const bf16x8*)(wla + o), ala, 0, 0, 0);
            aga = __builtin_amdgcn_mfma_f32_16x16x32_bf16(af[kk], *(const bf16x8*)(wga + o), aga, 0, 0, 0);
            alb = __builtin_amdgcn_mfma_f32_16x16x32_bf16(af[kk], *(const bf16x8*)(wlb + o), alb, 0, 0, 0);
            agb = __builtin_amdgcn_mfma_f32_16x16x32_bf16(af[kk], *(const bf16x8*)(wgb + o), agb, 0, 0, 0);
        }
        const float vla = vtab[col], vga = vtab[128 + col];
        const float vlb = vtab[256 + col], vgb = vtab[384 + col];
        #pragma unroll
        for (int r = 0; r < 4; ++r) {
            const float av = sigf(aga[r] + vga) * (ala[r] + vla);
            const float bv = sigf(agb[r] + vgb) * (alb[r] + vlb);
            cbuf[((size_t)batch * NA + t0 + q * 4 + r) * CC + col] = av * bv;
        }
    }
}

__global__ __launch_bounds__(64)
void kern_out(const float* __restrict__ x, const short* __restrict__ wbf,
              const float* __restrict__ vtab, const float* __restrict__ cbuf,
              float* __restrict__ out)
{
    __shared__ short kls[2][16][136];          // RAW bf16 k tiles (8.7 KB)
    __shared__ float kst[32][2];               // per-row {krs, kp} (256 B)
    // chunked XCD swizzle (grid 4096 = 8 x 512, bijective)
    const int bid   = blockIdx.x;
    const int swz   = (bid & 7) * 512 + (bid >> 3);
    const int batch = swz >> 11;               // 2048 waves per batch
    const int ib    = swz & 2047;
    const int row0  = ib * 32;                 // 32 rows per wave
    const int t0    = ib * 2;

    const int l   = threadIdx.x;
    const int idx = l & 31;                    // 32x32 row/col lane index
    const int q   = l >> 5;                    // k-half selector
    const int fl  = l * 8;

    // ---- 1: cbuf loads (lane-halves split the 2 t-groups, 4 ch each) ----
    const int c4 = idx * 4;
    const int t  = t0 + q;
    f32x4 cv[15];
    #pragma unroll
    for (int sx = 14; sx >= 0; --sx)
        cv[sx] = *(const f32x4*)(cbuf + ((size_t)batch * NA + ((t + sx + 2) & (NA - 1))) * CC + c4);

    // ---- 2: scan -> RAW bf16 k in LDS ----
    {
        short4v z = {0, 0, 0, 0};
        *(short4v*)&kls[q][15][c4] = z;
        float s0 = 0.f, s1 = 0.f, s2 = 0.f, s3 = 0.f;
        #pragma unroll
        for (int sx = 14; sx >= 0; --sx) {
            s0 += cv[sx][0]; s1 += cv[sx][1]; s2 += cv[sx][2]; s3 += cv[sx][3];
            short4v o; o[0] = nbf(s0); o[1] = nbf(s1); o[2] = nbf(s2); o[3] = nbf(s3);
            *(short4v*)&kls[q][sx][c4] = o;
        }
    }

    // ---- 3: issue x loads (32x32 A-frag layout: row idx, k = kb*16+q*8+j) ----
    const float* xr = x + ((size_t)batch * NN + row0 + idx) * DD + q * 8;
    f32x4 xv[8][2];
    #pragma unroll
    for (int kb = 0; kb < 8; ++kb) {
        xv[kb][0] = *(const f32x4*)(xr + kb * 16);
        xv[kb][1] = *(const f32x4*)(xr + kb * 16 + 4);
    }

    // ---- 4: k A-frags from LDS (raw, zero VALU pre-MFMA) + stats ----
    const int gi = idx >> 4, ri = idx & 15;
    short8v kr[8];
    #pragma unroll
    for (int kb = 0; kb < 8; ++kb)
        kr[kb] = *(const short8v*)&kls[gi][ri][kb * 16 + q * 8];

    {
        float ks = 0.f, kss = 0.f;
        #pragma unroll
        for (int kb = 0; kb < 8; ++kb)
            #pragma unroll
            for (int j = 0; j < 8; ++j) { const float f = bf2f(kr[kb][j]); ks += f; kss += f * f; }
        ks += __shfl_xor(ks, 32); kss += __shfl_xor(kss, 32);
        const float kmu = ks * (1.0f / 128.0f);
        const float krs = rsqrtf(kss * (1.0f / 128.0f) - kmu * kmu + 1e-5f);
        if (q == 0) { kst[idx][0] = krs; kst[idx][1] = -kmu * krs; }
    }
    // stats for this lane's C-rows: crow(r) = (r&3) + 8*(r>>2) + 4*q
    f32x2 kpr[16];
    #pragma unroll
    for (int r = 0; r < 16; ++r)
        kpr[r] = *(const f32x2*)&kst[(r & 3) + 8 * (r >> 2) + 4 * q][0];

    // ---- 5: LN(x) -> afx (1 shuffle pair: partner lane l^32 has other half) ----
    bf16x8 afx[8];
    {
        float s = 0.f, ss = 0.f;
        #pragma unroll
        for (int kb = 0; kb < 8; ++kb)
            #pragma unroll
            for (int h = 0; h < 2; ++h)
                #pragma unroll
                for (int j = 0; j < 4; ++j) { const float f = xv[kb][h][j]; s += f; ss += f * f; }
        s += __shfl_xor(s, 32); ss += __shfl_xor(ss, 32);
        const float mu = s * (1.0f / 128.0f);
        const float rs = rsqrtf(ss * (1.0f / 128.0f) - mu * mu + 1e-5f);
        const float p  = -mu * rs;
        #pragma unroll
        for (int kb = 0; kb < 8; ++kb) {
            short8v o;
            #pragma unroll
            for (int j = 0; j < 4; ++j) {
                o[j]     = nbf(xv[kb][0][j] * rs + p);
                o[4 + j] = nbf(xv[kb][1][j] * rs + p);
            }
            afx[kb] = s2b(o);
        }
    }

    // ---- 6: dual 32x32 GEMMs per nt-tile; algebraic-LN epilogue ----
    const short* wgo = wbf + 4 * WSZ;
    const short* wlo = wbf + 5 * WSZ;
    const float* vgo = vtab + 4 * 128;
    const float* vlo = vtab + 5 * 128;
    const float* slo = vtab + 768 + 5 * 128;
    #pragma unroll
    for (int nt = 0; nt < 4; ++nt) {
        f32x16 ag, ah;
        #pragma unroll
        for (int i = 0; i < 16; ++i) { ag[i] = 0.f; ah[i] = 0.f; }
        #pragma unroll
        for (int kb = 0; kb < 8; ++kb) {
            const int o = (nt * 8 + kb) * 512 + fl;
            ag = __builtin_amdgcn_mfma_f32_32x32x16_bf16(afx[kb], *(const bf16x8*)(wgo + o), ag, 0, 0, 0);
            ah = __builtin_amdgcn_mfma_f32_32x32x16_bf16(s2b(kr[kb]), *(const bf16x8*)(wlo + o), ah, 0, 0, 0);
        }
        const int   col = nt * 32 + idx;
        const float vg  = vgo[col];
        const float vl  = vlo[col];
        const float sl  = slo[col];
        #pragma unroll
        for (int r = 0; r < 16; ++r) {
            const int crow = (r & 3) + 8 * (r >> 2) + 4 * q;
            const size_t rowa = (size_t)batch * NN + row0 + crow;
            const float h = kpr[r][0] * ah[r] + (kpr[r][1] * sl + vl);
            out[rowa * DD + col] = sigf(ag[r] + vg) * h;
        }
    }
}

extern "C" void kernel_launch(void* const* d_in, const int* in_sizes, int n_in,
                              void* d_out, int out_size, void* d_ws, size_t ws_size,
                              hipStream_t stream)
{
    const float* x    = (const float*)d_in[0];
    const float* lnw  = (const float*)d_in[1];
    const float* lnb  = (const float*)d_in[2];
    const float* Wla  = (const float*)d_in[3];
    const float* bla  = (const float*)d_in[4];
    const float* Wga  = (const float*)d_in[5];
    const float* bga  = (const float*)d_in[6];
    const float* Wlb  = (const float*)d_in[7];
    const float* blb  = (const float*)d_in[8];
    const float* Wgb  = (const float*)d_in[9];
    const float* bgb  = (const float*)d_in[10];
    const float* lnow = (const float*)d_in[11];
    const float* lnob = (const float*)d_in[12];
    const float* Wgo  = (const float*)d_in[13];
    const float* bgo  = (const float*)d_in[14];
    const float* Wlo  = (const float*)d_in[15];
    const float* blo  = (const float*)d_in[16];

    float* cbuf = (float*)d_ws;                                      // 4 MB
    short* wbf  = (short*)((char*)d_ws + (size_t)BB * NA * CC * 4);  // 6*32KB
    float* vtab = (float*)((char*)wbf + 6 * WSZ * sizeof(short));    // 12*512B
    float* out  = (float*)d_out;

    hipLaunchKernelGGL(kern_wcvt, dim3(67), dim3(256), 0, stream,
                       Wla, Wga, Wlb, Wgb, Wgo, Wlo,
                       lnw, lnb, lnow, lnob,
                       bla, bga, blb, bgb, bgo, blo, wbf, vtab);
    hipLaunchKernelGGL(kern_ab, dim3(BB * 128), dim3(256), 0, stream,
                       x, wbf, vtab, cbuf);
    hipLaunchKernelGGL(kern_out, dim3(BB * 2048), dim3(64), 0, stream,
                       x, wbf, vtab, cbuf, out);
}